// Round 3
// baseline (229.589 us; speedup 1.0000x reference)
//
#include <hip/hip_runtime.h>

// B=4, N=1024, C=256, H=8.
// Reference math collapses: softmax over m sums to 1, and the final einsum
// 'bnmh,bnih->bnih' contracts only m of alpha -> out = vh elementwise.
// So: out[b,n,:] = linear_output^T @ flatten_ih(V-proj(v[b,n,:]) + bias_V)
// Precompose W[j'][j] = sum_{k=i*H+h} V[i,j',h] * L[k,j]  (256x256),
// bvec[j] = sum_k bias_V_flat[k] * L[k,j], then out = v @ W + bvec.

#define CDIM 256
#define HDIM 8
#define KDIM 2048  // CDIM*HDIM
#define ROWS 8     // rows per block in apply kernel

// Kernel 1: split-K GEMM composing W and bvec into workspace (atomicAdd).
// grid = (16 k-chunks of 128, 16 j'-tiles of 16), block = 256 (j).
__global__ __launch_bounds__(256) void compose_w(
    const float* __restrict__ V,    // [C, C, H] : V[i*2048 + j'*8 + h]
    const float* __restrict__ bV,   // [C, H] flat = [2048]
    const float* __restrict__ L,    // [2048, 256]
    float* __restrict__ W2,         // [256*256] (zeroed)
    float* __restrict__ bvec)       // [256] (zeroed)
{
    const int j   = threadIdx.x;
    const int k0  = blockIdx.x * 128;
    const int jp0 = blockIdx.y * 16;

    __shared__ float sV[128 * 16];  // sV[kk][r] = Vr[k0+kk][jp0+r]
    __shared__ float sb[128];

    for (int e = threadIdx.x; e < 128 * 16; e += 256) {
        const int kk = e >> 4, r = e & 15;
        const int k = k0 + kk;
        sV[e] = V[(k >> 3) * 2048 + (jp0 + r) * 8 + (k & 7)];
    }
    if (threadIdx.x < 128) sb[threadIdx.x] = bV[k0 + threadIdx.x];
    __syncthreads();

    float acc[16];
#pragma unroll
    for (int r = 0; r < 16; ++r) acc[r] = 0.f;
    float accb = 0.f;

    const float* Lp = L + k0 * 256 + j;
    for (int kk = 0; kk < 128; ++kk) {
        const float lv = Lp[kk * 256];          // coalesced, L2-resident
        accb += sb[kk] * lv;
#pragma unroll
        for (int r = 0; r < 16; ++r) acc[r] += sV[kk * 16 + r] * lv;  // LDS broadcast
    }
#pragma unroll
    for (int r = 0; r < 16; ++r)
        atomicAdd(&W2[(jp0 + r) * 256 + j], acc[r]);
    if (blockIdx.y == 0) atomicAdd(&bvec[j], accb);
}

// Kernel 2: out[row][j] = bvec[j] + sum_j' v[row][j'] * W2[j'][j]
// grid = 4096/ROWS blocks, block = 256 (j).
__global__ __launch_bounds__(256) void apply_w(
    const float* __restrict__ v,    // [4096, 256]
    const float* __restrict__ W2,   // [256, 256]
    const float* __restrict__ bvec, // [256]
    float* __restrict__ out)        // [4096, 256]
{
    const int j = threadIdx.x;
    const int row0 = blockIdx.x * ROWS;

    __shared__ float sv[ROWS * 256];
#pragma unroll
    for (int r = 0; r < ROWS; ++r)
        sv[r * 256 + j] = v[(row0 + r) * 256 + j];  // coalesced
    __syncthreads();

    const float b = bvec[j];
    float acc[ROWS];
#pragma unroll
    for (int r = 0; r < ROWS; ++r) acc[r] = b;

    for (int jp = 0; jp < 256; ++jp) {
        const float w = W2[jp * 256 + j];           // coalesced, L2-resident
#pragma unroll
        for (int r = 0; r < ROWS; ++r) acc[r] += sv[r * 256 + jp] * w;  // LDS broadcast
    }
#pragma unroll
    for (int r = 0; r < ROWS; ++r)
        out[(row0 + r) * 256 + j] = acc[r];
}

extern "C" void kernel_launch(void* const* d_in, const int* in_sizes, int n_in,
                              void* d_out, int out_size, void* d_ws, size_t ws_size,
                              hipStream_t stream) {
    // setup_inputs order: q(0) k(1) v(2) bias(3) atten_mask(4) Q(5) K(6) V(7)
    //                     bias_Q(8) bias_K(9) bias_V(10) linear_output(11)
    const float* v_in = (const float*)d_in[2];
    const float* V_w  = (const float*)d_in[7];
    const float* bV   = (const float*)d_in[10];
    const float* L    = (const float*)d_in[11];

    float* W2   = (float*)d_ws;           // 256*256 floats
    float* bvec = W2 + 256 * 256;         // 256 floats

    hipMemsetAsync(d_ws, 0, (256 * 256 + 256) * sizeof(float), stream);
    compose_w<<<dim3(16, 16), 256, 0, stream>>>(V_w, bV, L, W2, bvec);
    apply_w<<<4096 / ROWS, 256, 0, stream>>>(v_in, W2, bvec, (float*)d_out);
}

// Round 4
// 227.415 us; speedup vs baseline: 1.0096x; 1.0096x over previous
//
#include <hip/hip_runtime.h>

// B=4, N=1024, C=256, H=8.
// Reference math collapses: softmax over m sums to 1, and the final einsum
// 'bnmh,bnih->bnih' contracts only m of alpha -> out = vh elementwise.
// So: out[b,n,:] = linear_output^T @ flatten_ih(V-proj(v[b,n,:]) + bias_V)
// Precompose W[j'][j] = sum_{k=i*H+h} V[i,j',h] * L[k,j]  (256x256),
// bvec[j] = sum_k bias_V_flat[k] * L[k,j], then out = v @ W + bvec.
//
// R3 measured 229.6 us total; top-5 dispatches are all harness d_ws-poison
// fills (512 MB @ ~77 us each) -> we likely control only ~15-25 us.
// R4 change: apply_w inner loop ds_read_b32 x32 -> ds_read_b128 x8 per
// 4-jp group (m134: b128=12cyc vs b32=5.8cyc -> ~2x LDS cycle cut), plus
// float4 v staging. compose_w unchanged (isolate the variable).

#define ROWS 8     // rows per block in apply kernel

// Kernel 1: split-K GEMM composing W and bvec into workspace (atomicAdd).
// grid = (16 k-chunks of 128, 16 j'-tiles of 16), block = 256 (j).
__global__ __launch_bounds__(256) void compose_w(
    const float* __restrict__ V,    // [C, C, H] : V[i*2048 + j'*8 + h]
    const float* __restrict__ bV,   // [C, H] flat = [2048]
    const float* __restrict__ L,    // [2048, 256]
    float* __restrict__ W2,         // [256*256] (zeroed)
    float* __restrict__ bvec)       // [256] (zeroed)
{
    const int j   = threadIdx.x;
    const int k0  = blockIdx.x * 128;
    const int jp0 = blockIdx.y * 16;

    __shared__ float sV[128 * 16];  // sV[kk][r] = Vr[k0+kk][jp0+r]
    __shared__ float sb[128];

    for (int e = threadIdx.x; e < 128 * 16; e += 256) {
        const int kk = e >> 4, r = e & 15;
        const int k = k0 + kk;
        sV[e] = V[(k >> 3) * 2048 + (jp0 + r) * 8 + (k & 7)];
    }
    if (threadIdx.x < 128) sb[threadIdx.x] = bV[k0 + threadIdx.x];
    __syncthreads();

    float acc[16];
#pragma unroll
    for (int r = 0; r < 16; ++r) acc[r] = 0.f;
    float accb = 0.f;

    const float* Lp = L + k0 * 256 + j;
    for (int kk = 0; kk < 128; ++kk) {
        const float lv = Lp[kk * 256];          // coalesced, L2-resident
        accb += sb[kk] * lv;
#pragma unroll
        for (int r = 0; r < 16; ++r) acc[r] += sV[kk * 16 + r] * lv;  // LDS broadcast
    }
#pragma unroll
    for (int r = 0; r < 16; ++r)
        atomicAdd(&W2[(jp0 + r) * 256 + j], acc[r]);
    if (blockIdx.y == 0) atomicAdd(&bvec[j], accb);
}

// Kernel 2: out[row][j] = bvec[j] + sum_j' v[row][j'] * W2[j'][j]
// grid = 4096/ROWS blocks, block = 256 (j).
__global__ __launch_bounds__(256) void apply_w(
    const float* __restrict__ v,    // [4096, 256]
    const float* __restrict__ W2,   // [256, 256]
    const float* __restrict__ bvec, // [256]
    float* __restrict__ out)        // [4096, 256]
{
    const int j = threadIdx.x;
    const int row0 = blockIdx.x * ROWS;

    __shared__ float sv[ROWS * 256];
    // float4 staging: ROWS*256 floats = ROWS*64 float4s, coalesced dwordx4
    {
        const float4* v4 = reinterpret_cast<const float4*>(v + row0 * 256);
        float4* sv4 = reinterpret_cast<float4*>(sv);
#pragma unroll
        for (int e = threadIdx.x; e < ROWS * 64; e += 256)
            sv4[e] = v4[e];
    }
    __syncthreads();

    const float b = bvec[j];
    float acc[ROWS];
#pragma unroll
    for (int r = 0; r < ROWS; ++r) acc[r] = b;

    const float* Wp = W2 + j;
    for (int jp = 0; jp < 256; jp += 4) {
        // 4 coalesced, L2-resident W reads (independent -> overlapped)
        const float w0 = Wp[(jp + 0) * 256];
        const float w1 = Wp[(jp + 1) * 256];
        const float w2 = Wp[(jp + 2) * 256];
        const float w3 = Wp[(jp + 3) * 256];
#pragma unroll
        for (int r = 0; r < ROWS; ++r) {
            const float4 s = *reinterpret_cast<const float4*>(&sv[r * 256 + jp]);  // ds_read_b128 broadcast
            acc[r] += s.x * w0 + s.y * w1 + s.z * w2 + s.w * w3;
        }
    }
#pragma unroll
    for (int r = 0; r < ROWS; ++r)
        out[(row0 + r) * 256 + j] = acc[r];
}

extern "C" void kernel_launch(void* const* d_in, const int* in_sizes, int n_in,
                              void* d_out, int out_size, void* d_ws, size_t ws_size,
                              hipStream_t stream) {
    // setup_inputs order: q(0) k(1) v(2) bias(3) atten_mask(4) Q(5) K(6) V(7)
    //                     bias_Q(8) bias_K(9) bias_V(10) linear_output(11)
    const float* v_in = (const float*)d_in[2];
    const float* V_w  = (const float*)d_in[7];
    const float* bV   = (const float*)d_in[10];
    const float* L    = (const float*)d_in[11];

    float* W2   = (float*)d_ws;           // 256*256 floats
    float* bvec = W2 + 256 * 256;         // 256 floats

    hipMemsetAsync(d_ws, 0, (256 * 256 + 256) * sizeof(float), stream);
    compose_w<<<dim3(16, 16), 256, 0, stream>>>(V_w, bV, L, W2, bvec);
    apply_w<<<4096 / ROWS, 256, 0, stream>>>(v_in, W2, bvec, (float*)d_out);
}